// Round 3
// baseline (160.008 us; speedup 1.0000x reference)
//
#include <hip/hip_runtime.h>
#include <math.h>

#define NB 8
#define KC 64
#define S1C 5
#define CC 128
#define PP 1936
#define MM (KC * S1C)      /* 320 */
#define PT 64
#define NPT 31             /* ceil(1936/64) */
#define NTILE (NB * NPT)   /* 248 */
#define ALPHAF 1500.0f
#define EPSF 1e-12f

/* main-path ws (floats): part[248][64][128] ; ps[248][64] */
#define WS_PS   (NTILE * KC * CC)              /* 2,031,616 */
#define WS_MAIN_FLOATS (WS_PS + NTILE * KC)    /* 2,047,488 -> 8.19 MB */
/* fallback ws (floats): accC[8][64][128] ; accS[8][64] */
#define WS_ACCS (NB * KC * CC)
#define WS_FB_ZERO_BYTES ((size_t)(NB * KC * CC + NB * KC) * 4)

// ---------------------------------------------------------------------------
// k1: per (n, p-tile of 64), 1024 threads = 16 waves.
//   mode==0: write per-tile partial slabs (no atomics). mode==1: atomicAdd.
// ---------------------------------------------------------------------------
__global__ __launch_bounds__(1024) void k1_main(
    const float* __restrict__ x, const float* __restrict__ cen,
    float* __restrict__ sa_out, float* __restrict__ outC,
    float* __restrict__ outS, int mode)
{
    __shared__ float xs[CC][68];   // pad 68: phase-1 2-way (free), stage-C 4-way
    __shared__ float l0[KC][68];   // pad 68: 16B-aligned rows for b128 over p
    __shared__ float bias[MM];
    __shared__ float pm[16][PT];
    __shared__ float pe[16][PT];
    __shared__ float pmax[PT];
    __shared__ float prcs[PT];

    const int tid  = threadIdx.x;
    const int lane = tid & 63;
    const int wid  = tid >> 6;      // 0..15
    const int bx   = blockIdx.x;
    const int n    = bx / NPT;
    const int pt   = bx - n * NPT;
    const int p0   = pt * PT;

    // ---- stage x tile: xs[c][pp] = x[n][c][p0+pp] (zero-padded tail) ----
    const float* xn = x + (size_t)n * CC * PP;
    for (int idx = tid; idx < CC * 16; idx += 1024) {
        const int c = idx >> 4;
        const int q = idx & 15;
        const int p = p0 + q * 4;
        float4 v = make_float4(0.f, 0.f, 0.f, 0.f);
        if (p < PP) v = *(const float4*)(xn + (size_t)c * PP + p);  // PP%4==0: safe
        *(float4*)(&xs[c][q * 4]) = v;
    }
    // ---- bias: b[m] = -ALPHA * ||cen_m|| (threads 0..319, overlaps staging) ----
    if (tid < MM) {
        const float4* row = (const float4*)(cen + (size_t)tid * CC);
        float ss = 0.f;
#pragma unroll
        for (int c4 = 0; c4 < 32; ++c4) {
            const float4 v = row[c4];
            ss += v.x * v.x + v.y * v.y + v.z * v.z + v.w * v.w;
        }
        bias[tid] = -ALPHAF * sqrtf(ss);
    }
    __syncthreads();

    // ---- logits: 4 k per wave fully unrolled -> each xs read feeds 20 FMAs ----
    const float4* w4[4];
#pragma unroll
    for (int i = 0; i < 4; ++i) {
        const int k = __builtin_amdgcn_readfirstlane(wid + 16 * i);  // wave-uniform
        w4[i] = (const float4*)(cen + (size_t)k * S1C * CC);
    }
    float acc[4][5];
#pragma unroll
    for (int i = 0; i < 4; ++i)
#pragma unroll
        for (int s = 0; s < 5; ++s) acc[i][s] = 0.f;

#pragma unroll 4
    for (int c4 = 0; c4 < 32; ++c4) {
        const float x0 = xs[4 * c4 + 0][lane];
        const float x1 = xs[4 * c4 + 1][lane];
        const float x2 = xs[4 * c4 + 2][lane];
        const float x3 = xs[4 * c4 + 3][lane];
#pragma unroll
        for (int i = 0; i < 4; ++i) {
#pragma unroll
            for (int s = 0; s < 5; ++s) {
                const float4 w = w4[i][s * 32 + c4];
                acc[i][s] += w.x * x0 + w.y * x1 + w.z * x2 + w.w * x3;
            }
        }
    }

    float beta_r[4];
#pragma unroll
    for (int i = 0; i < 4; ++i) {
        const int k = wid + 16 * i;
        float lg[5];
#pragma unroll
        for (int s = 0; s < 5; ++s)
            lg[s] = 2.f * ALPHAF * acc[i][s] + bias[k * S1C + s];
        const float m5 = fmaxf(fmaxf(fmaxf(lg[0], lg[1]), fmaxf(lg[2], lg[3])), lg[4]);
        const float e0 = __expf(lg[0] - m5);
        const float den = e0 + __expf(lg[1] - m5) + __expf(lg[2] - m5) +
                          __expf(lg[3] - m5) + __expf(lg[4] - m5);
        beta_r[i] = e0 / den;
        l0[k][lane] = lg[0];
    }
    __syncthreads();

    // ---- alpha softmax over K, parallel across 16 waves (two-pass) ----
    {
        float lg[4], mx = -3.0e38f;
#pragma unroll
        for (int j = 0; j < 4; ++j) {
            lg[j] = l0[4 * wid + j][lane];
            mx = fmaxf(mx, lg[j]);
        }
        float se = 0.f;
#pragma unroll
        for (int j = 0; j < 4; ++j) se += __expf(lg[j] - mx);
        pm[wid][lane] = mx;
        pe[wid][lane] = se;
    }
    __syncthreads();
    if (tid < PT) {
        float gm = -3.0e38f;
#pragma unroll
        for (int w = 0; w < 16; ++w) gm = fmaxf(gm, pm[w][tid]);
        float s = 0.f;
#pragma unroll
        for (int w = 0; w < 16; ++w) s += pe[w][tid] * __expf(pm[w][tid] - gm);
        pmax[tid] = gm;
        prcs[tid] = 1.0f / s;
    }
    __syncthreads();

    // ---- soft_assign out + w_assign into l0 (zero for pad p) ----
    const bool valid = (p0 + lane) < PP;
    float* san = sa_out + (size_t)n * KC * PP;
#pragma unroll
    for (int i = 0; i < 4; ++i) {
        const int k = wid + 16 * i;
        const float sa = __expf(l0[k][lane] - pmax[lane]) * prcs[lane] * beta_r[i];
        if (valid) san[(size_t)k * PP + p0 + lane] = sa;
        l0[k][lane] = valid ? (1.0f + sa) : 0.0f;
    }
    __syncthreads();

    // ---- partial C: thread = (k-pair kk,kk+32) x (4 c at stride 32), b128 over p ----
    const int cq = tid & 31;        // c = cq + 32*j
    const int kk = tid >> 5;        // rows kk, kk+32
    float acc2[2][4];
#pragma unroll
    for (int a = 0; a < 2; ++a)
#pragma unroll
        for (int j = 0; j < 4; ++j) acc2[a][j] = 0.f;

#pragma unroll 4
    for (int P = 0; P < 16; ++P) {
        const int p4 = P * 4;
        const float4 wv0 = *(const float4*)(&l0[kk][p4]);
        const float4 wv1 = *(const float4*)(&l0[kk + 32][p4]);
#pragma unroll
        for (int j = 0; j < 4; ++j) {
            const float4 xv = *(const float4*)(&xs[cq + 32 * j][p4]);
            acc2[0][j] += wv0.x * xv.x + wv0.y * xv.y + wv0.z * xv.z + wv0.w * xv.w;
            acc2[1][j] += wv1.x * xv.x + wv1.y * xv.y + wv1.z * xv.z + wv1.w * xv.w;
        }
    }

    if (mode == 0) {
        float* dst = outC + (size_t)bx * KC * CC;
#pragma unroll
        for (int j = 0; j < 4; ++j) {
            dst[kk * CC + cq + 32 * j]        = acc2[0][j];
            dst[(kk + 32) * CC + cq + 32 * j] = acc2[1][j];
        }
        if (tid < KC) {
            float s = 0.f;
            for (int p = 0; p < PT; ++p) s += l0[tid][p];
            outS[(size_t)bx * KC + tid] = s;
        }
    } else {
        float* dst = outC + (size_t)n * KC * CC;
#pragma unroll
        for (int j = 0; j < 4; ++j) {
            atomicAdd(&dst[kk * CC + cq + 32 * j], acc2[0][j]);
            atomicAdd(&dst[(kk + 32) * CC + cq + 32 * j], acc2[1][j]);
        }
        if (tid < KC) {
            float s = 0.f;
            for (int p = 0; p < PT; ++p) s += l0[tid][p];
            atomicAdd(&outS[n * KC + tid], s);
        }
    }
}

// ---------------------------------------------------------------------------
// k2 (slab mode): reduce 31 partial slabs, subtract rep*Swa, normalize, /8
// ---------------------------------------------------------------------------
__global__ __launch_bounds__(128) void k2_slab(
    const float* __restrict__ part, const float* __restrict__ ps,
    const float* __restrict__ cen, float* __restrict__ flat)
{
    __shared__ float w2[2];
    const int b = blockIdx.x;        // n*64 + k
    const int n = b >> 6;
    const int k = b & 63;
    const int c = threadIdx.x;       // 0..127
    const float* pb = part + ((size_t)n * NPT) * KC * CC + (size_t)k * CC + c;
    float v = 0.f;
#pragma unroll 8
    for (int pt = 0; pt < NPT; ++pt) v += pb[(size_t)pt * KC * CC];
    const float* psb = ps + (size_t)n * NPT * KC + k;
    float sw = 0.f;
#pragma unroll
    for (int pt = 0; pt < NPT; ++pt) sw += psb[(size_t)pt * KC];
    v -= cen[(size_t)k * S1C * CC + c] * sw;

    float ss = v * v;
#pragma unroll
    for (int off = 32; off > 0; off >>= 1) ss += __shfl_down(ss, off);
    if ((c & 63) == 0) w2[c >> 6] = ss;
    __syncthreads();
    const float norm = sqrtf(w2[0] + w2[1]);
    // flat-level norm is exactly sqrt(64)=8 (every row unit-norm, >> EPS)
    const float scale = 1.0f / (fmaxf(norm, EPSF) * 8.0f);
    flat[(size_t)b * CC + c] = v * scale;
}

// ---------------------------------------------------------------------------
// k2 (fallback/atomic mode): same finalize from accC/accS
// ---------------------------------------------------------------------------
__global__ __launch_bounds__(128) void k2_final(
    const float* __restrict__ accC, const float* __restrict__ accS,
    const float* __restrict__ cen, float* __restrict__ flat)
{
    __shared__ float w2[2];
    const int b = blockIdx.x;        // n*64 + k
    const int k = b & 63;
    const int c = threadIdx.x;       // 0..127
    const float v = accC[(size_t)b * CC + c] -
                    cen[(size_t)k * S1C * CC + c] * accS[b];
    float ss = v * v;
#pragma unroll
    for (int off = 32; off > 0; off >>= 1) ss += __shfl_down(ss, off);
    if ((c & 63) == 0) w2[c >> 6] = ss;
    __syncthreads();
    const float norm = sqrtf(w2[0] + w2[1]);
    const float scale = 1.0f / (fmaxf(norm, EPSF) * 8.0f);
    flat[(size_t)b * CC + c] = v * scale;
}

// ---------------------------------------------------------------------------
extern "C" void kernel_launch(void* const* d_in, const int* in_sizes, int n_in,
                              void* d_out, int out_size, void* d_ws, size_t ws_size,
                              hipStream_t stream) {
    const float* x   = (const float*)d_in[0];   // [8][128][44][44]
    const float* cen = (const float*)d_in[1];   // [64][5][128]
    float* out  = (float*)d_out;
    float* flat = out;                           // [8][8192]
    float* sa   = out + (size_t)NB * KC * CC;    // [8][64][1][1936]
    float* ws   = (float*)d_ws;

    if (ws_size >= (size_t)WS_MAIN_FLOATS * 4) {
        // main path: 2 dispatches, no atomics, no memset
        float* part = ws;
        float* ps   = ws + WS_PS;
        k1_main<<<NTILE, 1024, 0, stream>>>(x, cen, sa, part, ps, 0);
        k2_slab<<<NB * KC, 128, 0, stream>>>(part, ps, cen, flat);
    } else {
        // fallback: proven R2 path (memset + atomics)
        float* accC = ws;
        float* accS = ws + NB * KC * CC;
        hipMemsetAsync(d_ws, 0, WS_FB_ZERO_BYTES, stream);
        k1_main<<<NTILE, 1024, 0, stream>>>(x, cen, sa, accC, accS, 1);
        k2_final<<<NB * KC, 128, 0, stream>>>(accC, accS, cen, flat);
    }
}

// Round 4
// 103.725 us; speedup vs baseline: 1.5426x; 1.5426x over previous
//
#include <hip/hip_runtime.h>
#include <math.h>

#define NB 8
#define KC 64
#define S1C 5
#define CC 128
#define PP 1936
#define MM (KC * S1C)      /* 320 */
#define PT 64
#define NPT 31             /* ceil(1936/64) */
#define NTILE (NB * NPT)   /* 248 */
#define ALPHAF 1500.0f
#define EPSF 1e-12f

/* main-path ws (floats): part[248][64][128] ; ps[248][64] */
#define WS_PS   (NTILE * KC * CC)              /* 2,031,616 */
#define WS_MAIN_FLOATS (WS_PS + NTILE * KC)    /* 2,047,488 -> 8.19 MB */
/* fallback ws (floats): accC[8][64][128] ; accS[8][64] */
#define WS_FB_ZERO_BYTES ((size_t)(NB * KC * CC + NB * KC) * 4)

// ---------------------------------------------------------------------------
// k1: per (n, p-tile of 64), 1024 threads = 16 waves.
// __launch_bounds__(1024, 4): 4 waves/EU -> 128-VGPR budget. R3 regression
// root cause: default target was 8 waves/EU (64 VGPR) and the unrolled
// logits body (~100 live regs) spilled/rematerialized -> 3x VALU insts.
// ---------------------------------------------------------------------------
__global__ __launch_bounds__(1024, 4) void k1_main(
    const float* __restrict__ x, const float* __restrict__ cen,
    float* __restrict__ sa_out, float* __restrict__ outC,
    float* __restrict__ outS, int mode)
{
    __shared__ float xs[CC][68];   // pad 68: 16B-aligned rows, conflicts free/2-way
    __shared__ float l0[KC][68];   // pad 68: 16B-aligned rows for b128 over p
    __shared__ float bias[MM];
    __shared__ float pm[16][PT];
    __shared__ float pe[16][PT];
    __shared__ float pmax[PT];
    __shared__ float prcs[PT];

    const int tid  = threadIdx.x;
    const int lane = tid & 63;
    const int wid  = tid >> 6;      // 0..15
    const int bx   = blockIdx.x;
    const int n    = bx / NPT;
    const int pt   = bx - n * NPT;
    const int p0   = pt * PT;

    // ---- stage x tile: xs[c][pp] = x[n][c][p0+pp] (zero-padded tail) ----
    const float* xn = x + (size_t)n * CC * PP;
    for (int idx = tid; idx < CC * 16; idx += 1024) {
        const int c = idx >> 4;
        const int q = idx & 15;
        const int p = p0 + q * 4;
        float4 v = make_float4(0.f, 0.f, 0.f, 0.f);
        if (p < PP) v = *(const float4*)(xn + (size_t)c * PP + p);  // PP%4==0: safe
        *(float4*)(&xs[c][q * 4]) = v;
    }
    // ---- bias: b[m] = -ALPHA * ||cen_m|| (threads 0..319, overlaps staging) ----
    if (tid < MM) {
        const float4* row = (const float4*)(cen + (size_t)tid * CC);
        float ss = 0.f;
#pragma unroll
        for (int c4 = 0; c4 < 32; ++c4) {
            const float4 v = row[c4];
            ss += v.x * v.x + v.y * v.y + v.z * v.z + v.w * v.w;
        }
        bias[tid] = -ALPHAF * sqrtf(ss);
    }
    __syncthreads();

    // ---- logits: 4 k per wave, single pass -> each xs read feeds 20 FMAs ----
    const float4* w4[4];
#pragma unroll
    for (int i = 0; i < 4; ++i) {
        const int k = __builtin_amdgcn_readfirstlane(wid + 16 * i);  // wave-uniform
        w4[i] = (const float4*)(cen + (size_t)k * S1C * CC);
    }
    float acc[4][5];
#pragma unroll
    for (int i = 0; i < 4; ++i)
#pragma unroll
        for (int s = 0; s < 5; ++s) acc[i][s] = 0.f;

#pragma unroll 2
    for (int c4 = 0; c4 < 32; ++c4) {
        const float x0 = xs[4 * c4 + 0][lane];
        const float x1 = xs[4 * c4 + 1][lane];
        const float x2 = xs[4 * c4 + 2][lane];
        const float x3 = xs[4 * c4 + 3][lane];
#pragma unroll
        for (int i = 0; i < 4; ++i) {
#pragma unroll
            for (int s = 0; s < 5; ++s) {
                const float4 w = w4[i][s * 32 + c4];
                acc[i][s] += w.x * x0 + w.y * x1 + w.z * x2 + w.w * x3;
            }
        }
    }

    float beta_r[4];
#pragma unroll
    for (int i = 0; i < 4; ++i) {
        const int k = wid + 16 * i;
        float lg[5];
#pragma unroll
        for (int s = 0; s < 5; ++s)
            lg[s] = 2.f * ALPHAF * acc[i][s] + bias[k * S1C + s];
        const float m5 = fmaxf(fmaxf(fmaxf(lg[0], lg[1]), fmaxf(lg[2], lg[3])), lg[4]);
        const float e0 = __expf(lg[0] - m5);
        const float den = e0 + __expf(lg[1] - m5) + __expf(lg[2] - m5) +
                          __expf(lg[3] - m5) + __expf(lg[4] - m5);
        beta_r[i] = e0 / den;
        l0[k][lane] = lg[0];
    }
    __syncthreads();

    // ---- alpha softmax over K, parallel across 16 waves (two-pass) ----
    {
        float lg[4], mx = -3.0e38f;
#pragma unroll
        for (int j = 0; j < 4; ++j) {
            lg[j] = l0[4 * wid + j][lane];
            mx = fmaxf(mx, lg[j]);
        }
        float se = 0.f;
#pragma unroll
        for (int j = 0; j < 4; ++j) se += __expf(lg[j] - mx);
        pm[wid][lane] = mx;
        pe[wid][lane] = se;
    }
    __syncthreads();
    if (tid < PT) {
        float gm = -3.0e38f;
#pragma unroll
        for (int w = 0; w < 16; ++w) gm = fmaxf(gm, pm[w][tid]);
        float s = 0.f;
#pragma unroll
        for (int w = 0; w < 16; ++w) s += pe[w][tid] * __expf(pm[w][tid] - gm);
        pmax[tid] = gm;
        prcs[tid] = 1.0f / s;
    }
    __syncthreads();

    // ---- soft_assign out + w_assign into l0 (zero for pad p) ----
    const bool valid = (p0 + lane) < PP;
    float* san = sa_out + (size_t)n * KC * PP;
#pragma unroll
    for (int i = 0; i < 4; ++i) {
        const int k = wid + 16 * i;
        const float sa = __expf(l0[k][lane] - pmax[lane]) * prcs[lane] * beta_r[i];
        if (valid) san[(size_t)k * PP + p0 + lane] = sa;
        l0[k][lane] = valid ? (1.0f + sa) : 0.0f;
    }
    __syncthreads();

    // ---- partial C: thread = (k-pair kk,kk+32) x (4 c at stride 32), b128 over p ----
    const int cq = tid & 31;        // c = cq + 32*j
    const int kk = tid >> 5;        // rows kk, kk+32
    float acc2[2][4];
#pragma unroll
    for (int a = 0; a < 2; ++a)
#pragma unroll
        for (int j = 0; j < 4; ++j) acc2[a][j] = 0.f;

#pragma unroll 4
    for (int P = 0; P < 16; ++P) {
        const int p4 = P * 4;
        const float4 wv0 = *(const float4*)(&l0[kk][p4]);
        const float4 wv1 = *(const float4*)(&l0[kk + 32][p4]);
#pragma unroll
        for (int j = 0; j < 4; ++j) {
            const float4 xv = *(const float4*)(&xs[cq + 32 * j][p4]);
            acc2[0][j] += wv0.x * xv.x + wv0.y * xv.y + wv0.z * xv.z + wv0.w * xv.w;
            acc2[1][j] += wv1.x * xv.x + wv1.y * xv.y + wv1.z * xv.z + wv1.w * xv.w;
        }
    }

    if (mode == 0) {
        float* dst = outC + (size_t)bx * KC * CC;
#pragma unroll
        for (int j = 0; j < 4; ++j) {
            dst[kk * CC + cq + 32 * j]        = acc2[0][j];
            dst[(kk + 32) * CC + cq + 32 * j] = acc2[1][j];
        }
        if (tid < KC) {
            float s = 0.f;
            for (int p = 0; p < PT; ++p) s += l0[tid][p];
            outS[(size_t)bx * KC + tid] = s;
        }
    } else {
        float* dst = outC + (size_t)n * KC * CC;
#pragma unroll
        for (int j = 0; j < 4; ++j) {
            atomicAdd(&dst[kk * CC + cq + 32 * j], acc2[0][j]);
            atomicAdd(&dst[(kk + 32) * CC + cq + 32 * j], acc2[1][j]);
        }
        if (tid < KC) {
            float s = 0.f;
            for (int p = 0; p < PT; ++p) s += l0[tid][p];
            atomicAdd(&outS[n * KC + tid], s);
        }
    }
}

// ---------------------------------------------------------------------------
// k2 (slab mode): reduce 31 partial slabs, subtract rep*Swa, normalize, /8
// ---------------------------------------------------------------------------
__global__ __launch_bounds__(128) void k2_slab(
    const float* __restrict__ part, const float* __restrict__ ps,
    const float* __restrict__ cen, float* __restrict__ flat)
{
    __shared__ float w2[2];
    const int b = blockIdx.x;        // n*64 + k
    const int n = b >> 6;
    const int k = b & 63;
    const int c = threadIdx.x;       // 0..127
    const float* pb = part + ((size_t)n * NPT) * KC * CC + (size_t)k * CC + c;
    float v = 0.f;
#pragma unroll 8
    for (int pt = 0; pt < NPT; ++pt) v += pb[(size_t)pt * KC * CC];
    const float* psb = ps + (size_t)n * NPT * KC + k;
    float sw = 0.f;
#pragma unroll
    for (int pt = 0; pt < NPT; ++pt) sw += psb[(size_t)pt * KC];
    v -= cen[(size_t)k * S1C * CC + c] * sw;

    float ss = v * v;
#pragma unroll
    for (int off = 32; off > 0; off >>= 1) ss += __shfl_down(ss, off);
    if ((c & 63) == 0) w2[c >> 6] = ss;
    __syncthreads();
    const float norm = sqrtf(w2[0] + w2[1]);
    // flat-level norm is exactly sqrt(64)=8 (every row unit-norm, >> EPS)
    const float scale = 1.0f / (fmaxf(norm, EPSF) * 8.0f);
    flat[(size_t)b * CC + c] = v * scale;
}

// ---------------------------------------------------------------------------
// k2 (fallback/atomic mode): same finalize from accC/accS
// ---------------------------------------------------------------------------
__global__ __launch_bounds__(128) void k2_final(
    const float* __restrict__ accC, const float* __restrict__ accS,
    const float* __restrict__ cen, float* __restrict__ flat)
{
    __shared__ float w2[2];
    const int b = blockIdx.x;        // n*64 + k
    const int k = b & 63;
    const int c = threadIdx.x;       // 0..127
    const float v = accC[(size_t)b * CC + c] -
                    cen[(size_t)k * S1C * CC + c] * accS[b];
    float ss = v * v;
#pragma unroll
    for (int off = 32; off > 0; off >>= 1) ss += __shfl_down(ss, off);
    if ((c & 63) == 0) w2[c >> 6] = ss;
    __syncthreads();
    const float norm = sqrtf(w2[0] + w2[1]);
    const float scale = 1.0f / (fmaxf(norm, EPSF) * 8.0f);
    flat[(size_t)b * CC + c] = v * scale;
}

// ---------------------------------------------------------------------------
extern "C" void kernel_launch(void* const* d_in, const int* in_sizes, int n_in,
                              void* d_out, int out_size, void* d_ws, size_t ws_size,
                              hipStream_t stream) {
    const float* x   = (const float*)d_in[0];   // [8][128][44][44]
    const float* cen = (const float*)d_in[1];   // [64][5][128]
    float* out  = (float*)d_out;
    float* flat = out;                           // [8][8192]
    float* sa   = out + (size_t)NB * KC * CC;    // [8][64][1][1936]
    float* ws   = (float*)d_ws;

    if (ws_size >= (size_t)WS_MAIN_FLOATS * 4) {
        // main path: 2 dispatches, no atomics, no memset
        float* part = ws;
        float* ps   = ws + WS_PS;
        k1_main<<<NTILE, 1024, 0, stream>>>(x, cen, sa, part, ps, 0);
        k2_slab<<<NB * KC, 128, 0, stream>>>(part, ps, cen, flat);
    } else {
        // fallback: proven R2 path (memset + atomics)
        float* accC = ws;
        float* accS = ws + NB * KC * CC;
        hipMemsetAsync(d_ws, 0, WS_FB_ZERO_BYTES, stream);
        k1_main<<<NTILE, 1024, 0, stream>>>(x, cen, sa, accC, accS, 1);
        k2_final<<<NB * KC, 128, 0, stream>>>(accC, accS, cen, flat);
    }
}